// Round 2
// baseline (895.415 us; speedup 1.0000x reference)
//
#include <hip/hip_runtime.h>
#include <hip/hip_fp16.h>
#include <hip/hip_cooperative_groups.h>
#include <math.h>

namespace cg = cooperative_groups;

// NormVoxels R7:
//  - R6 post-mortem: brick is latency-bound (time ~ 1/occupancy). Revert to
//    diff-form s_acc (24.6KB) and raise occupancy to the 32-wave cap with
//    512-thread blocks (4 blocks/CU x 8 waves = 100% vs 61% measured at R5).
//  - wave-parallel 25-bin prefix scan (shfl) replaces serial tid0 loop.
//  - keep binary search + __expf.
//  - fuse memset+key_hist+scanA+scanC+scatter into ONE cooperative kernel
//    (grid 1024x256, co-resident, grid.sync between phases): 6 dispatches -> 2.
// d_in: [0]=t(i32,N) [1]=pos(f32,N*3) [2]=lr(f32,1) [3]=sigma(f32,N)
//       [4]=target_norm(f32,N*3) [5]=voxel_array(f32,8*128^3*3)
// d_out: value(f32,N*3) ++ new_voxel(f32,8*128^3*3)

#define GRES 128
#define NBINS (8 * 128 * 128)      // key = t(3)|x(7)|y(7)  (17 bits)
#define SCAN_VBLOCKS 512           // 256 bins per virtual scan block
#define PRESORT_BLOCKS 1024        // 4 blocks/CU, co-resident (cooperative)
constexpr float RMIN_F = -1.5f;
constexpr float STEP_F = 3.0f / 128.0f;  // exact in fp32

__global__ __launch_bounds__(256, 4) void presort_kernel(
    const int*   __restrict__ t,     const float* __restrict__ pos,
    const float* __restrict__ lr_p,  const float* __restrict__ sigma,
    const float* __restrict__ target,
    unsigned* __restrict__ keys,     unsigned* __restrict__ hist,
    unsigned* __restrict__ binstart, unsigned* __restrict__ partial,
    uint4*    __restrict__ sorted,   int N)
{
    cg::grid_group grid = cg::this_grid();
    const int tid  = threadIdx.x;
    const int gtid = blockIdx.x * 256 + tid;
    const int gsz  = PRESORT_BLOCKS * 256;

    // Phase 0: zero hist
    for (int i = gtid; i < NBINS; i += gsz) hist[i] = 0u;
    grid.sync();

    // Phase 1: key + free within-bin rank via atomic return
    for (int i = gtid; i < N; i += gsz) {
        float px = pos[3 * i + 0] - RMIN_F;
        float py = pos[3 * i + 1] - RMIN_F;
        int cx = min((int)floorf(px / STEP_F), GRES - 1);
        int cy = min((int)floorf(py / STEP_F), GRES - 1);
        unsigned key  = ((unsigned)t[i] << 14) | ((unsigned)cx << 7) | (unsigned)cy;
        unsigned rank = atomicAdd(&hist[key], 1u);
        keys[i] = (key << 15) | rank;                // 17b key | 15b rank
    }
    grid.sync();

    // Phase 2 (scanA): virtual blocks 0..511 do a local 256-bin scan
    __shared__ unsigned sh[256];
    if (blockIdx.x < SCAN_VBLOCKS) {
        const int gid = blockIdx.x * 256 + tid;
        unsigned x = hist[gid];
        sh[tid] = x;
        __syncthreads();
        for (int off = 1; off < 256; off <<= 1) {
            unsigned v = (tid >= off) ? sh[tid - off] : 0u;
            __syncthreads();
            sh[tid] += v;
            __syncthreads();
        }
        binstart[gid] = sh[tid] - x;               // local exclusive
        if (tid == 255) partial[blockIdx.x] = sh[255];
    }
    grid.sync();

    // Phase 3 (scanC): each virtual block reduces partial[0..vb) + applies
    if (blockIdx.x < SCAN_VBLOCKS) {
        __shared__ unsigned s_w[4];
        unsigned loc = 0;
        for (int i = tid; i < blockIdx.x; i += 256) loc += partial[i];
        #pragma unroll
        for (int off = 32; off > 0; off >>= 1) loc += __shfl_down(loc, off);
        if ((tid & 63) == 0) s_w[tid >> 6] = loc;
        __syncthreads();
        const unsigned off0 = s_w[0] + s_w[1] + s_w[2] + s_w[3];
        const int gid = blockIdx.x * 256 + tid;
        binstart[gid] += off0;
        if (gid == 0) binstart[NBINS] = (unsigned)N;
    }
    grid.sync();

    // Phase 4 (scatter): slot = binstart[key] + rank, no atomics
    const float lr0 = lr_p[0];
    for (int i = gtid; i < N; i += gsz) {
        unsigned kr   = keys[i];
        unsigned key  = kr >> 15;
        unsigned rank = kr & 0x7fffu;
        unsigned slot = binstart[key] + rank;

        float px = pos[3 * i + 0] - RMIN_F;
        float py = pos[3 * i + 1] - RMIN_F;
        float pz = pos[3 * i + 2] - RMIN_F;
        float u = fmodf(px, STEP_F) / STEP_F;
        float v = fmodf(py, STEP_F) / STEP_F;
        float w = fmodf(pz, STEP_F) / STEP_F;
        int   mz = min((int)floorf(pz / STEP_F), GRES - 1);

        unsigned qu = (unsigned)(u * 2047.0f + 0.5f);
        unsigned qv = (unsigned)(v * 2047.0f + 0.5f);
        unsigned qw = (unsigned)(w * 1023.0f + 0.5f);

        float lrsw = lr0 * (1.0f - __expf(-sigma[i]));

        unsigned hx = (unsigned)__half_as_ushort(__float2half(target[3 * i + 0]));
        unsigned hy = (unsigned)__half_as_ushort(__float2half(target[3 * i + 1]));
        unsigned hz = (unsigned)__half_as_ushort(__float2half(target[3 * i + 2]));
        unsigned hl = (unsigned)__half_as_ushort(__float2half(lrsw));

        uint4 p;
        p.x = (qu << 21) | (qv << 10) | qw;
        p.y = ((unsigned)i << 7) | (unsigned)mz;        // idx:20 | mz:7
        p.z = hx | (hy << 16);
        p.w = hz | (hl << 16);
        sorted[slot] = p;
    }
}

__global__ __launch_bounds__(512, 8) void brick_kernel(
    const unsigned* __restrict__ binstart,
    const uint4*    __restrict__ sorted,
    const float*    __restrict__ voxel_in,
    float*          __restrict__ out_value,
    float*          __restrict__ out_voxel)
{
    __shared__ __align__(16) float s_acc[4 * 4 * 128 * 3];   // 24576 B
    __shared__ unsigned s_start[25];
    __shared__ unsigned s_pref[26];

    // XCD-slab swizzle: each XCD gets one contiguous t-slab (L2 halo reuse).
    const int vb = ((blockIdx.x & 7) << 10) | (blockIdx.x >> 3);
    const int t  = vb >> 10;
    const int bx = (vb >> 5) & 31;
    const int by = vb & 31;
    const int x0 = bx << 2, y0 = by << 2;
    const int tid = threadIdx.x;
    const size_t tbase = (size_t)t * (GRES * GRES * GRES * 3);

    float4* s_acc4 = (float4*)s_acc;
    for (int q = tid; q < 16 * 96; q += 512) s_acc4[q] = make_float4(0.f, 0.f, 0.f, 0.f);

    // wave-parallel halo-bin setup + prefix scan (wave 0 only)
    if (tid < 64) {
        unsigned st = 0, cnt = 0;
        if (tid < 25) {
            int dxb = tid / 5 - 1, dyb = tid % 5 - 1;
            int cx = x0 + dxb, cy = y0 + dyb;
            if (cx >= 0 && cx < GRES && cy >= 0 && cy < GRES) {
                unsigned key = ((unsigned)t << 14) | ((unsigned)cx << 7) | (unsigned)cy;
                st  = binstart[key];
                cnt = binstart[key + 1] - st;
            }
            s_start[tid] = st;
        }
        unsigned x = cnt;
        #pragma unroll
        for (int off = 1; off < 32; off <<= 1) {
            unsigned y = __shfl_up(x, off);
            if (tid >= off) x += y;
        }
        if (tid < 25) s_pref[tid + 1] = x;          // inclusive scan
        if (tid == 0) s_pref[0] = 0;
    }
    __syncthreads();
    const int P = (int)s_pref[25];

    for (int j = tid; j < P; j += 512) {
        // binary search: largest b in [0,24] with s_pref[b] <= j
        int b = 0;
        #pragma unroll
        for (int s = 16; s > 0; s >>= 1) {
            int nb = b + s;
            if (nb <= 24 && s_pref[nb] <= (unsigned)j) b = nb;
        }
        const int dxb = b / 5 - 1, dyb = b % 5 - 1;
        const int cx = x0 + dxb, cy = y0 + dyb;
        const unsigned g = s_start[b] + ((unsigned)j - s_pref[b]);

        const uint4 p = sorted[g];
        const float u = (float)(p.x >> 21)           * (1.0f / 2047.0f);
        const float v = (float)((p.x >> 10) & 2047u) * (1.0f / 2047.0f);
        const float w = (float)(p.x & 1023u)         * (1.0f / 1023.0f);
        const int  mz  = (int)(p.y & 127u);
        const int  idx = (int)(p.y >> 7);
        const float tx = __half2float(__ushort_as_half((unsigned short)(p.z & 0xffffu)));
        const float ty = __half2float(__ushort_as_half((unsigned short)(p.z >> 16)));
        const float tz = __half2float(__ushort_as_half((unsigned short)(p.w & 0xffffu)));
        const float lrsw = __half2float(__ushort_as_half((unsigned short)(p.w >> 16)));

        const int xs1 = min(cx + 1, GRES - 1);
        const int ys1 = min(cy + 1, GRES - 1);
        const int zs1 = min(mz + 1, GRES - 1);

        // Phase 1: issue ALL 8 corner gathers unconditionally (always in
        // bounds after clamp) -> 8-deep MLP, no control flow in the way.
        float a[8][3];
        #pragma unroll
        for (int k = 0; k < 8; ++k) {
            const int xi = (k & 1) ? xs1 : cx;
            const int yi = (k & 2) ? ys1 : cy;
            const int zi = (k & 4) ? zs1 : mz;
            const float* vp = voxel_in + tbase + (((size_t)xi * GRES + yi) * GRES + zi) * 3;
            a[k][0] = vp[0];
            a[k][1] = vp[1];
            a[k][2] = vp[2];
        }

        float c[8];
        c[0] = (1.f - u) * (1.f - v) * (1.f - w);
        c[1] =        u  * (1.f - v) * (1.f - w);
        c[2] = (1.f - u) *        v  * (1.f - w);
        c[3] =        u  *        v  * (1.f - w);
        c[4] = (1.f - u) * (1.f - v) *        w;
        c[5] =        u  * (1.f - v) *        w;
        c[6] = (1.f - u) *        v  *        w;
        c[7] =        u  *        v  *        w;

        const bool owner = (dxb >= 0) && (dyb >= 0);

        // Phase 2: predicated value accumulation + LDS atomic scatter.
        float vx = 0.f, vy = 0.f, vz = 0.f;
        #pragma unroll
        for (int k = 0; k < 8; ++k) {
            if (owner) {
                vx += c[k] * a[k][0];
                vy += c[k] * a[k][1];
                vz += c[k] * a[k][2];
            }
            const int xi = (k & 1) ? xs1 : cx;
            const int yi = (k & 2) ? ys1 : cy;
            const int sxi = xi - x0, syi = yi - y0;
            if (sxi >= 0 && sxi < 4 && syi >= 0 && syi < 4) {
                const int zi = (k & 4) ? zs1 : mz;
                const float lam = 1.0f / (1.0f + __expf(-lrsw * c[k]));
                const int sa = ((sxi * 4 + syi) * 128 + zi) * 3;
                atomicAdd(&s_acc[sa + 0], lam * (tx - a[k][0]));
                atomicAdd(&s_acc[sa + 1], lam * (ty - a[k][1]));
                atomicAdd(&s_acc[sa + 2], lam * (tz - a[k][2]));
            }
        }
        if (owner) {
            out_value[3 * idx + 0] = vx;
            out_value[3 * idx + 1] = vy;
            out_value[3 * idx + 2] = vz;
        }
    }
    __syncthreads();

    // Coalesced write-out: out = voxel_in (L2/L3-hot re-read) + diff.
    for (int q = tid; q < 16 * 96; q += 512) {
        int row = q / 96, r = q - row * 96;
        int ox = row >> 2, oy = row & 3;
        const size_t coff = tbase + (size_t)(x0 + ox) * 49152 + (size_t)(y0 + oy) * 384;
        float4 a = *((const float4*)(voxel_in + coff) + r);
        float4 d = s_acc4[q];
        *((float4*)(out_voxel + coff) + r) =
            make_float4(a.x + d.x, a.y + d.y, a.z + d.z, a.w + d.w);
    }
}

extern "C" void kernel_launch(void* const* d_in, const int* in_sizes, int n_in,
                              void* d_out, int out_size, void* d_ws, size_t ws_size,
                              hipStream_t stream) {
    const int*   t      = (const int*)  d_in[0];
    const float* pos    = (const float*)d_in[1];
    const float* lr     = (const float*)d_in[2];
    const float* sigma  = (const float*)d_in[3];
    const float* target = (const float*)d_in[4];
    const float* voxel  = (const float*)d_in[5];

    const int N = in_sizes[0];              // 1048576 points

    float* out_value = (float*)d_out;
    float* out_voxel = out_value + (size_t)3 * N;

    // ws: sorted(16B*N=16MB) | keys(4MB) | hist | binstart(+1) | partial
    uint4*    sorted   = (uint4*)d_ws;
    unsigned* keys     = (unsigned*)(sorted + (size_t)N);
    unsigned* hist     = keys + N;
    unsigned* binstart = hist + NBINS;
    unsigned* partial  = binstart + (NBINS + 1);

    int n = N;
    void* args[] = { (void*)&t, (void*)&pos, (void*)&lr, (void*)&sigma,
                     (void*)&target, (void*)&keys, (void*)&hist,
                     (void*)&binstart, (void*)&partial, (void*)&sorted,
                     (void*)&n };
    hipLaunchCooperativeKernel((const void*)presort_kernel,
                               dim3(PRESORT_BLOCKS), dim3(256),
                               args, 0, stream);
    brick_kernel<<<8192, 512, 0, stream>>>(binstart, sorted, voxel,
                                           out_value, out_voxel);
}

// Round 3
// 515.141 us; speedup vs baseline: 1.7382x; 1.7382x over previous
//
#include <hip/hip_runtime.h>
#include <hip/hip_fp16.h>
#include <math.h>

// NormVoxels R8: single-pass placement sort (fixed-cap bins + overflow list).
//  R7 post-mortem: the pre-brick pipeline costs ~340us (2 scattered-op passes
//  + scans + keys round-trip), brick only 181. Counting sort's 2nd pass exists
//  only to learn binstart -> replace with direct placement at key*CAP+rank
//  (rank from the same atomicAdd that built the histogram). Overflow (rank>=16,
//  ~700 pts expected at lambda=8) goes to a side list all bricks sweep.
//  One pass over points instead of two; scanA/scanC/keys eliminated.
//  brick_kernel = proven R5 config (256thr, 24.6KB LDS) + cap/overflow mode.
//  Runtime ws_size guard falls back to the proven R5 5-kernel path.
// d_in: [0]=t(i32,N) [1]=pos(f32,N*3) [2]=lr(f32,1) [3]=sigma(f32,N)
//       [4]=target_norm(f32,N*3) [5]=voxel_array(f32,8*128^3*3)
// d_out: value(f32,N*3) ++ new_voxel(f32,8*128^3*3)

#define GRES 128
#define NBINS (8 * 128 * 128)      // key = t(3)|x(7)|y(7)  (17 bits)
#define CAP 16                     // payload slots per bin
#define OVF_MAX 16384              // overflow list capacity (expected ~700)
#define SCAN_BLOCKS 512            // fallback path
constexpr float RMIN_F = -1.5f;
constexpr float STEP_F = 3.0f / 128.0f;  // exact in fp32

// ---------- payload construction (shared by place + fallback scatter) ------
__device__ __forceinline__ uint4 make_payload(
    int i, float px, float py, float pz, int mz,
    const float* __restrict__ target, float lrsw)
{
    float u = fmodf(px, STEP_F) / STEP_F;
    float v = fmodf(py, STEP_F) / STEP_F;
    float w = fmodf(pz, STEP_F) / STEP_F;
    unsigned qu = (unsigned)(u * 2047.0f + 0.5f);
    unsigned qv = (unsigned)(v * 2047.0f + 0.5f);
    unsigned qw = (unsigned)(w * 1023.0f + 0.5f);
    unsigned hx = (unsigned)__half_as_ushort(__float2half(target[3 * i + 0]));
    unsigned hy = (unsigned)__half_as_ushort(__float2half(target[3 * i + 1]));
    unsigned hz = (unsigned)__half_as_ushort(__float2half(target[3 * i + 2]));
    unsigned hl = (unsigned)__half_as_ushort(__float2half(lrsw));
    uint4 p;
    p.x = (qu << 21) | (qv << 10) | qw;
    p.y = ((unsigned)i << 7) | (unsigned)mz;        // idx:20 | mz:7
    p.z = hx | (hy << 16);
    p.w = hz | (hl << 16);
    return p;
}

// ---------- single-pass placement ------------------------------------------
__global__ __launch_bounds__(256) void place_kernel(
    const int*   __restrict__ t,     const float* __restrict__ pos,
    const float* __restrict__ lr_p,  const float* __restrict__ sigma,
    const float* __restrict__ target,
    unsigned* __restrict__ hist,     uint4* __restrict__ bins,
    unsigned* __restrict__ ovfcnt,   unsigned* __restrict__ ovf_key,
    uint4*    __restrict__ ovf_pay,  int N)
{
    int i = blockIdx.x * blockDim.x + threadIdx.x;
    if (i >= N) return;
    float px = pos[3 * i + 0] - RMIN_F;
    float py = pos[3 * i + 1] - RMIN_F;
    float pz = pos[3 * i + 2] - RMIN_F;
    int cx = min((int)floorf(px / STEP_F), GRES - 1);
    int cy = min((int)floorf(py / STEP_F), GRES - 1);
    int mz = min((int)floorf(pz / STEP_F), GRES - 1);
    float lrsw = lr_p[0] * (1.0f - __expf(-sigma[i]));
    uint4 p = make_payload(i, px, py, pz, mz, target, lrsw);
    unsigned key  = ((unsigned)t[i] << 14) | ((unsigned)cx << 7) | (unsigned)cy;
    unsigned rank = atomicAdd(&hist[key], 1u);
    if (rank < CAP) {
        bins[(size_t)key * CAP + rank] = p;
    } else {
        unsigned o = atomicAdd(ovfcnt, 1u);
        if (o < OVF_MAX) { ovf_key[o] = key; ovf_pay[o] = p; }
    }
}

// ---------- fallback path (R5-proven): key_hist / scanA / scanC / scatter ---
__global__ __launch_bounds__(256) void key_hist_kernel(
    const int* __restrict__ t, const float* __restrict__ pos,
    unsigned* __restrict__ keys, unsigned* __restrict__ hist, int N)
{
    int i = blockIdx.x * blockDim.x + threadIdx.x;
    if (i >= N) return;
    float px = pos[3 * i + 0] - RMIN_F;
    float py = pos[3 * i + 1] - RMIN_F;
    int cx = min((int)floorf(px / STEP_F), GRES - 1);
    int cy = min((int)floorf(py / STEP_F), GRES - 1);
    unsigned key  = ((unsigned)t[i] << 14) | ((unsigned)cx << 7) | (unsigned)cy;
    unsigned rank = atomicAdd(&hist[key], 1u);
    keys[i] = (key << 15) | rank;                    // 17b key | 15b rank
}

__global__ __launch_bounds__(256) void scanA_kernel(
    const unsigned* __restrict__ hist, unsigned* __restrict__ binstart,
    unsigned* __restrict__ partial)
{
    __shared__ unsigned sh[256];
    const int tid = threadIdx.x;
    const int gid = blockIdx.x * 256 + tid;
    unsigned x = hist[gid];
    sh[tid] = x;
    __syncthreads();
    for (int off = 1; off < 256; off <<= 1) {
        unsigned v = (tid >= off) ? sh[tid - off] : 0u;
        __syncthreads();
        sh[tid] += v;
        __syncthreads();
    }
    binstart[gid] = sh[tid] - x;
    if (tid == 255) partial[blockIdx.x] = sh[255];
}

__global__ __launch_bounds__(256) void scanC_kernel(
    unsigned* __restrict__ binstart, const unsigned* __restrict__ partial, int N)
{
    __shared__ unsigned s_w[4];
    unsigned loc = 0;
    for (int i = threadIdx.x; i < blockIdx.x; i += 256) loc += partial[i];
    #pragma unroll
    for (int off = 32; off > 0; off >>= 1) loc += __shfl_down(loc, off);
    if ((threadIdx.x & 63) == 0) s_w[threadIdx.x >> 6] = loc;
    __syncthreads();
    const unsigned off0 = s_w[0] + s_w[1] + s_w[2] + s_w[3];
    const int gid = blockIdx.x * 256 + threadIdx.x;
    binstart[gid] += off0;
    if (gid == 0) binstart[NBINS] = (unsigned)N;
}

__global__ __launch_bounds__(256) void scatter_kernel(
    const float* __restrict__ pos, const float* __restrict__ lr_p,
    const float* __restrict__ sigma, const float* __restrict__ target,
    const unsigned* __restrict__ keys, const unsigned* __restrict__ binstart,
    uint4* __restrict__ sorted, int N)
{
    int i = blockIdx.x * blockDim.x + threadIdx.x;
    if (i >= N) return;
    unsigned kr   = keys[i];
    unsigned key  = kr >> 15;
    unsigned rank = kr & 0x7fffu;
    unsigned slot = binstart[key] + rank;
    float px = pos[3 * i + 0] - RMIN_F;
    float py = pos[3 * i + 1] - RMIN_F;
    float pz = pos[3 * i + 2] - RMIN_F;
    int   mz = min((int)floorf(pz / STEP_F), GRES - 1);
    float lrsw = lr_p[0] * (1.0f - __expf(-sigma[i]));
    sorted[slot] = make_payload(i, px, py, pz, mz, target, lrsw);
}

// ---------- per-event processing (shared by main loop + overflow sweep) -----
__device__ __forceinline__ void process_event(
    const uint4 p, const int cx, const int cy,
    const int x0, const int y0, const size_t tbase,
    const float* __restrict__ voxel_in,
    float* __restrict__ out_value, float* __restrict__ s_acc)
{
    const float u = (float)(p.x >> 21)           * (1.0f / 2047.0f);
    const float v = (float)((p.x >> 10) & 2047u) * (1.0f / 2047.0f);
    const float w = (float)(p.x & 1023u)         * (1.0f / 1023.0f);
    const int  mz  = (int)(p.y & 127u);
    const int  idx = (int)(p.y >> 7);
    const float tx = __half2float(__ushort_as_half((unsigned short)(p.z & 0xffffu)));
    const float ty = __half2float(__ushort_as_half((unsigned short)(p.z >> 16)));
    const float tz = __half2float(__ushort_as_half((unsigned short)(p.w & 0xffffu)));
    const float lrsw = __half2float(__ushort_as_half((unsigned short)(p.w >> 16)));

    const int xs1 = min(cx + 1, GRES - 1);
    const int ys1 = min(cy + 1, GRES - 1);
    const int zs1 = min(mz + 1, GRES - 1);

    // Phase 1: all 8 corner gathers unconditionally -> 8-deep MLP.
    float a[8][3];
    #pragma unroll
    for (int k = 0; k < 8; ++k) {
        const int xi = (k & 1) ? xs1 : cx;
        const int yi = (k & 2) ? ys1 : cy;
        const int zi = (k & 4) ? zs1 : mz;
        const float* vp = voxel_in + tbase + (((size_t)xi * GRES + yi) * GRES + zi) * 3;
        a[k][0] = vp[0];
        a[k][1] = vp[1];
        a[k][2] = vp[2];
    }

    float c[8];
    c[0] = (1.f - u) * (1.f - v) * (1.f - w);
    c[1] =        u  * (1.f - v) * (1.f - w);
    c[2] = (1.f - u) *        v  * (1.f - w);
    c[3] =        u  *        v  * (1.f - w);
    c[4] = (1.f - u) * (1.f - v) *        w;
    c[5] =        u  * (1.f - v) *        w;
    c[6] = (1.f - u) *        v  *        w;
    c[7] =        u  *        v  *        w;

    const bool owner = (cx >= x0) && (cy >= y0);

    // Phase 2: predicated value accumulation + LDS atomic scatter.
    float vx = 0.f, vy = 0.f, vz = 0.f;
    #pragma unroll
    for (int k = 0; k < 8; ++k) {
        if (owner) {
            vx += c[k] * a[k][0];
            vy += c[k] * a[k][1];
            vz += c[k] * a[k][2];
        }
        const int xi = (k & 1) ? xs1 : cx;
        const int yi = (k & 2) ? ys1 : cy;
        const int sxi = xi - x0, syi = yi - y0;
        if (sxi >= 0 && sxi < 4 && syi >= 0 && syi < 4) {
            const int zi = (k & 4) ? zs1 : mz;
            const float lam = 1.0f / (1.0f + __expf(-lrsw * c[k]));
            const int sa = ((sxi * 4 + syi) * 128 + zi) * 3;
            atomicAdd(&s_acc[sa + 0], lam * (tx - a[k][0]));
            atomicAdd(&s_acc[sa + 1], lam * (ty - a[k][1]));
            atomicAdd(&s_acc[sa + 2], lam * (tz - a[k][2]));
        }
    }
    if (owner) {
        out_value[3 * idx + 0] = vx;
        out_value[3 * idx + 1] = vy;
        out_value[3 * idx + 2] = vz;
    }
}

// cap==0: counts = binstart prefix array, payloads compact in `sorted`.
// cap>0 : counts = hist (clamped at cap), payloads at key*cap, + overflow list.
__global__ __launch_bounds__(256) void brick_kernel(
    const unsigned* __restrict__ counts,
    const uint4*    __restrict__ sorted,
    const float*    __restrict__ voxel_in,
    float*          __restrict__ out_value,
    float*          __restrict__ out_voxel,
    int cap,
    const unsigned* __restrict__ ovf_key,
    const uint4*    __restrict__ ovf_pay,
    const unsigned* __restrict__ ovfcnt)
{
    __shared__ __align__(16) float s_acc[4 * 4 * 128 * 3];   // 24576 B
    __shared__ unsigned s_start[25];
    __shared__ unsigned s_pref[26];
    __shared__ unsigned s_novf;

    // XCD-slab swizzle: each XCD gets one contiguous t-slab (L2 halo reuse).
    const int vb = ((blockIdx.x & 7) << 10) | (blockIdx.x >> 3);
    const int t  = vb >> 10;
    const int bx = (vb >> 5) & 31;
    const int by = vb & 31;
    const int x0 = bx << 2, y0 = by << 2;
    const int tid = threadIdx.x;
    const size_t tbase = (size_t)t * (GRES * GRES * GRES * 3);

    float4* s_acc4 = (float4*)s_acc;
    for (int q = tid; q < 16 * 96; q += 256) s_acc4[q] = make_float4(0.f, 0.f, 0.f, 0.f);

    // wave-parallel halo-bin setup + prefix scan (wave 0)
    if (tid < 64) {
        unsigned st = 0, cnt = 0;
        if (tid < 25) {
            int dxb = tid / 5 - 1, dyb = tid % 5 - 1;
            int cx = x0 + dxb, cy = y0 + dyb;
            if (cx >= 0 && cx < GRES && cy >= 0 && cy < GRES) {
                unsigned key = ((unsigned)t << 14) | ((unsigned)cx << 7) | (unsigned)cy;
                if (cap > 0) {
                    st  = key * (unsigned)cap;
                    cnt = min(counts[key], (unsigned)cap);
                } else {
                    st  = counts[key];
                    cnt = counts[key + 1] - st;
                }
            }
            s_start[tid] = st;
        }
        unsigned x = cnt;
        #pragma unroll
        for (int off = 1; off < 32; off <<= 1) {
            unsigned y = __shfl_up(x, off);
            if (tid >= off) x += y;
        }
        if (tid < 25) s_pref[tid + 1] = x;          // inclusive scan
        if (tid == 0) s_pref[0] = 0;
    }
    if (tid == 64) s_novf = (cap > 0) ? *ovfcnt : 0u;
    __syncthreads();
    const int P = (int)s_pref[25];

    for (int j = tid; j < P; j += 256) {
        // binary search: largest b in [0,24] with s_pref[b] <= j
        int b = 0;
        #pragma unroll
        for (int s = 16; s > 0; s >>= 1) {
            int nb = b + s;
            if (nb <= 24 && s_pref[nb] <= (unsigned)j) b = nb;
        }
        const int cx = x0 + b / 5 - 1, cy = y0 + b % 5 - 1;
        const unsigned g = s_start[b] + ((unsigned)j - s_pref[b]);
        process_event(sorted[g], cx, cy, x0, y0, tbase, voxel_in, out_value, s_acc);
    }

    // overflow sweep (cap mode only; expected ~700 entries total)
    if (cap > 0) {
        const unsigned novf = min(s_novf, (unsigned)OVF_MAX);
        for (unsigned o = tid; o < novf; o += 256) {
            const unsigned key = ovf_key[o];
            if ((int)(key >> 14) != t) continue;
            const int ocx = (int)((key >> 7) & 127u), ocy = (int)(key & 127u);
            const int dxb = ocx - x0, dyb = ocy - y0;
            if (dxb < -1 || dxb > 3 || dyb < -1 || dyb > 3) continue;
            process_event(ovf_pay[o], ocx, ocy, x0, y0, tbase, voxel_in, out_value, s_acc);
        }
    }
    __syncthreads();

    // Coalesced write-out: out = voxel_in (L2/L3-hot re-read) + diff.
    for (int q = tid; q < 16 * 96; q += 256) {
        int row = q / 96, r = q - row * 96;
        int ox = row >> 2, oy = row & 3;
        const size_t coff = tbase + (size_t)(x0 + ox) * 49152 + (size_t)(y0 + oy) * 384;
        float4 a = *((const float4*)(voxel_in + coff) + r);
        float4 d = s_acc4[q];
        *((float4*)(out_voxel + coff) + r) =
            make_float4(a.x + d.x, a.y + d.y, a.z + d.z, a.w + d.w);
    }
}

extern "C" void kernel_launch(void* const* d_in, const int* in_sizes, int n_in,
                              void* d_out, int out_size, void* d_ws, size_t ws_size,
                              hipStream_t stream) {
    const int*   t      = (const int*)  d_in[0];
    const float* pos    = (const float*)d_in[1];
    const float* lr     = (const float*)d_in[2];
    const float* sigma  = (const float*)d_in[3];
    const float* target = (const float*)d_in[4];
    const float* voxel  = (const float*)d_in[5];

    const int N = in_sizes[0];              // 1048576 points

    float* out_value = (float*)d_out;
    float* out_voxel = out_value + (size_t)3 * N;

    const int block = 256;
    const int grid  = (N + block - 1) / block;

    const size_t need = (size_t)NBINS * CAP * 16 + (size_t)NBINS * 4 + 64
                      + (size_t)OVF_MAX * 4 + (size_t)OVF_MAX * 16;   // ~33.4MB

    if (ws_size >= need) {
        // ws: bins(32MB) | hist(512KB) | ovfcnt(64B) | ovf_key(64KB) | ovf_pay(256KB)
        uint4*    bins    = (uint4*)d_ws;
        unsigned* hist    = (unsigned*)(bins + (size_t)NBINS * CAP);
        unsigned* ovfcnt  = hist + NBINS;
        unsigned* ovf_key = ovfcnt + 16;
        uint4*    ovf_pay = (uint4*)(ovf_key + OVF_MAX);

        hipMemsetAsync(hist, 0, NBINS * sizeof(unsigned) + 64, stream);
        place_kernel<<<grid, block, 0, stream>>>(t, pos, lr, sigma, target,
                                                 hist, bins, ovfcnt, ovf_key,
                                                 ovf_pay, N);
        brick_kernel<<<8192, 256, 0, stream>>>(hist, bins, voxel,
                                               out_value, out_voxel,
                                               CAP, ovf_key, ovf_pay, ovfcnt);
    } else {
        // fallback: proven R5 5-kernel path (~21MB)
        uint4*    sorted   = (uint4*)d_ws;
        unsigned* keys     = (unsigned*)(sorted + (size_t)N);
        unsigned* hist     = keys + N;
        unsigned* binstart = hist + NBINS;
        unsigned* partial  = binstart + (NBINS + 1);

        hipMemsetAsync(hist, 0, NBINS * sizeof(unsigned), stream);
        key_hist_kernel<<<grid, block, 0, stream>>>(t, pos, keys, hist, N);
        scanA_kernel<<<SCAN_BLOCKS, 256, 0, stream>>>(hist, binstart, partial);
        scanC_kernel<<<SCAN_BLOCKS, 256, 0, stream>>>(binstart, partial, N);
        scatter_kernel<<<grid, block, 0, stream>>>(pos, lr, sigma, target, keys,
                                                   binstart, sorted, N);
        brick_kernel<<<8192, 256, 0, stream>>>(binstart, sorted, voxel,
                                               out_value, out_voxel,
                                               0, nullptr, nullptr, nullptr);
    }
}

// Round 4
// 507.429 us; speedup vs baseline: 1.7646x; 1.0152x over previous
//
#include <hip/hip_runtime.h>
#include <hip/hip_fp16.h>
#include <math.h>

// NormVoxels R9: paired-z gather + polynomial sigmoid.
//  R8 post-mortem: brick moves only compulsory bytes (450MB) but at 2.4/6.3
//  TB/s -> transaction/latency bound, not BW. Corners (k,k+4) differ only in
//  z -> one dwordx4+dwordx2 (6 contiguous floats) replaces ~4-6 scalar lane
//  requests; 8 gathers/event -> 4 paired loads, zero VGPR/occupancy cost.
//  sigmoid(x), |x|<=0.1: 0.5+x/4-x^3/48 (err<6e-5), __expf fallback branch.
//  Single-pass placement sort (R8) kept: hist atomic rank -> bins[key*16+rank],
//  overflow side list; ws_size guard falls back to 5-kernel count-sort path.
// d_in: [0]=t(i32,N) [1]=pos(f32,N*3) [2]=lr(f32,1) [3]=sigma(f32,N)
//       [4]=target_norm(f32,N*3) [5]=voxel_array(f32,8*128^3*3)
// d_out: value(f32,N*3) ++ new_voxel(f32,8*128^3*3)

#define GRES 128
#define NBINS (8 * 128 * 128)      // key = t(3)|x(7)|y(7)  (17 bits)
#define CAP 16                     // payload slots per bin
#define OVF_MAX 16384              // overflow list capacity (expected ~700)
#define SCAN_BLOCKS 512            // fallback path
constexpr float RMIN_F = -1.5f;
constexpr float STEP_F = 3.0f / 128.0f;  // exact in fp32

// 4-byte-aligned vector loads (voxel stride is 12B; gfx950 global_load_dwordxN
// only needs dword alignment).
typedef float f32x4a4 __attribute__((ext_vector_type(4), aligned(4)));
typedef float f32x2a4 __attribute__((ext_vector_type(2), aligned(4)));

__device__ __forceinline__ float fast_sigmoid(float x) {
    // |x| = |lrsw*c| <= lr in practice (~0.1). Cubic Taylor, err<6e-5 @ |x|<0.5.
    if (__builtin_expect(fabsf(x) < 0.5f, 1)) {
        return fmaf(x, fmaf(x * x, -(1.0f / 48.0f), 0.25f), 0.5f);
    }
    return 1.0f / (1.0f + __expf(-x));
}

// ---------- payload construction (shared by place + fallback scatter) ------
__device__ __forceinline__ uint4 make_payload(
    int i, float px, float py, float pz, int mz,
    const float* __restrict__ target, float lrsw)
{
    float u = fmodf(px, STEP_F) / STEP_F;
    float v = fmodf(py, STEP_F) / STEP_F;
    float w = fmodf(pz, STEP_F) / STEP_F;
    unsigned qu = (unsigned)(u * 2047.0f + 0.5f);
    unsigned qv = (unsigned)(v * 2047.0f + 0.5f);
    unsigned qw = (unsigned)(w * 1023.0f + 0.5f);
    unsigned hx = (unsigned)__half_as_ushort(__float2half(target[3 * i + 0]));
    unsigned hy = (unsigned)__half_as_ushort(__float2half(target[3 * i + 1]));
    unsigned hz = (unsigned)__half_as_ushort(__float2half(target[3 * i + 2]));
    unsigned hl = (unsigned)__half_as_ushort(__float2half(lrsw));
    uint4 p;
    p.x = (qu << 21) | (qv << 10) | qw;
    p.y = ((unsigned)i << 7) | (unsigned)mz;        // idx:20 | mz:7
    p.z = hx | (hy << 16);
    p.w = hz | (hl << 16);
    return p;
}

// ---------- single-pass placement ------------------------------------------
__global__ __launch_bounds__(256) void place_kernel(
    const int*   __restrict__ t,     const float* __restrict__ pos,
    const float* __restrict__ lr_p,  const float* __restrict__ sigma,
    const float* __restrict__ target,
    unsigned* __restrict__ hist,     uint4* __restrict__ bins,
    unsigned* __restrict__ ovfcnt,   unsigned* __restrict__ ovf_key,
    uint4*    __restrict__ ovf_pay,  int N)
{
    int i = blockIdx.x * blockDim.x + threadIdx.x;
    if (i >= N) return;
    float px = pos[3 * i + 0] - RMIN_F;
    float py = pos[3 * i + 1] - RMIN_F;
    float pz = pos[3 * i + 2] - RMIN_F;
    int cx = min((int)floorf(px / STEP_F), GRES - 1);
    int cy = min((int)floorf(py / STEP_F), GRES - 1);
    int mz = min((int)floorf(pz / STEP_F), GRES - 1);
    float lrsw = lr_p[0] * (1.0f - __expf(-sigma[i]));
    uint4 p = make_payload(i, px, py, pz, mz, target, lrsw);
    unsigned key  = ((unsigned)t[i] << 14) | ((unsigned)cx << 7) | (unsigned)cy;
    unsigned rank = atomicAdd(&hist[key], 1u);
    if (rank < CAP) {
        bins[(size_t)key * CAP + rank] = p;
    } else {
        unsigned o = atomicAdd(ovfcnt, 1u);
        if (o < OVF_MAX) { ovf_key[o] = key; ovf_pay[o] = p; }
    }
}

// ---------- fallback path (R5-proven): key_hist / scanA / scanC / scatter ---
__global__ __launch_bounds__(256) void key_hist_kernel(
    const int* __restrict__ t, const float* __restrict__ pos,
    unsigned* __restrict__ keys, unsigned* __restrict__ hist, int N)
{
    int i = blockIdx.x * blockDim.x + threadIdx.x;
    if (i >= N) return;
    float px = pos[3 * i + 0] - RMIN_F;
    float py = pos[3 * i + 1] - RMIN_F;
    int cx = min((int)floorf(px / STEP_F), GRES - 1);
    int cy = min((int)floorf(py / STEP_F), GRES - 1);
    unsigned key  = ((unsigned)t[i] << 14) | ((unsigned)cx << 7) | (unsigned)cy;
    unsigned rank = atomicAdd(&hist[key], 1u);
    keys[i] = (key << 15) | rank;                    // 17b key | 15b rank
}

__global__ __launch_bounds__(256) void scanA_kernel(
    const unsigned* __restrict__ hist, unsigned* __restrict__ binstart,
    unsigned* __restrict__ partial)
{
    __shared__ unsigned sh[256];
    const int tid = threadIdx.x;
    const int gid = blockIdx.x * 256 + tid;
    unsigned x = hist[gid];
    sh[tid] = x;
    __syncthreads();
    for (int off = 1; off < 256; off <<= 1) {
        unsigned v = (tid >= off) ? sh[tid - off] : 0u;
        __syncthreads();
        sh[tid] += v;
        __syncthreads();
    }
    binstart[gid] = sh[tid] - x;
    if (tid == 255) partial[blockIdx.x] = sh[255];
}

__global__ __launch_bounds__(256) void scanC_kernel(
    unsigned* __restrict__ binstart, const unsigned* __restrict__ partial, int N)
{
    __shared__ unsigned s_w[4];
    unsigned loc = 0;
    for (int i = threadIdx.x; i < blockIdx.x; i += 256) loc += partial[i];
    #pragma unroll
    for (int off = 32; off > 0; off >>= 1) loc += __shfl_down(loc, off);
    if ((threadIdx.x & 63) == 0) s_w[threadIdx.x >> 6] = loc;
    __syncthreads();
    const unsigned off0 = s_w[0] + s_w[1] + s_w[2] + s_w[3];
    const int gid = blockIdx.x * 256 + threadIdx.x;
    binstart[gid] += off0;
    if (gid == 0) binstart[NBINS] = (unsigned)N;
}

__global__ __launch_bounds__(256) void scatter_kernel(
    const float* __restrict__ pos, const float* __restrict__ lr_p,
    const float* __restrict__ sigma, const float* __restrict__ target,
    const unsigned* __restrict__ keys, const unsigned* __restrict__ binstart,
    uint4* __restrict__ sorted, int N)
{
    int i = blockIdx.x * blockDim.x + threadIdx.x;
    if (i >= N) return;
    unsigned kr   = keys[i];
    unsigned key  = kr >> 15;
    unsigned rank = kr & 0x7fffu;
    unsigned slot = binstart[key] + rank;
    float px = pos[3 * i + 0] - RMIN_F;
    float py = pos[3 * i + 1] - RMIN_F;
    float pz = pos[3 * i + 2] - RMIN_F;
    int   mz = min((int)floorf(pz / STEP_F), GRES - 1);
    float lrsw = lr_p[0] * (1.0f - __expf(-sigma[i]));
    sorted[slot] = make_payload(i, px, py, pz, mz, target, lrsw);
}

// ---------- per-event processing (shared by main loop + overflow sweep) -----
// Paired-z gather: corners (p2, p2+4) share (x,y), z = mz / min(mz+1,127).
// Their 6 floats are contiguous at z = zb = min(mz,126): one dwordx4 + one
// dwordx2 lane-request per pair instead of up to 6 scalar dwords.
__device__ __forceinline__ void process_event(
    const uint4 p, const int cx, const int cy,
    const int x0, const int y0, const size_t tbase,
    const float* __restrict__ voxel_in,
    float* __restrict__ out_value, float* __restrict__ s_acc)
{
    const float u = (float)(p.x >> 21)           * (1.0f / 2047.0f);
    const float v = (float)((p.x >> 10) & 2047u) * (1.0f / 2047.0f);
    const float w = (float)(p.x & 1023u)         * (1.0f / 1023.0f);
    const int  mz  = (int)(p.y & 127u);
    const int  idx = (int)(p.y >> 7);
    const float tx = __half2float(__ushort_as_half((unsigned short)(p.z & 0xffffu)));
    const float ty = __half2float(__ushort_as_half((unsigned short)(p.z >> 16)));
    const float tz = __half2float(__ushort_as_half((unsigned short)(p.w & 0xffffu)));
    const float lrsw = __half2float(__ushort_as_half((unsigned short)(p.w >> 16)));

    const int xs1 = min(cx + 1, GRES - 1);
    const int ys1 = min(cy + 1, GRES - 1);
    const int zs1 = min(mz + 1, GRES - 1);
    const int zb  = min(mz, GRES - 2);
    const bool ztop = (mz == GRES - 1);

    // Phase 1: 4 paired gathers, all issued before use -> deep MLP.
    float lo[4][3], hi[4][3];
    #pragma unroll
    for (int q = 0; q < 4; ++q) {
        const int xi = (q & 1) ? xs1 : cx;
        const int yi = (q & 2) ? ys1 : cy;
        const float* vp = voxel_in + tbase + (((size_t)xi * GRES + yi) * GRES + zb) * 3;
        f32x4a4 f0 = *(const f32x4a4*)vp;        // z=zb:{x,y,z}, z=zb+1:{x}
        f32x2a4 f1 = *(const f32x2a4*)(vp + 4);  // z=zb+1:{y,z}
        hi[q][0] = f0.w; hi[q][1] = f1.x; hi[q][2] = f1.y;
        lo[q][0] = ztop ? f0.w : f0.x;
        lo[q][1] = ztop ? f1.x : f0.y;
        lo[q][2] = ztop ? f1.y : f0.z;
    }

    float c[8];
    c[0] = (1.f - u) * (1.f - v) * (1.f - w);
    c[1] =        u  * (1.f - v) * (1.f - w);
    c[2] = (1.f - u) *        v  * (1.f - w);
    c[3] =        u  *        v  * (1.f - w);
    c[4] = (1.f - u) * (1.f - v) *        w;
    c[5] =        u  * (1.f - v) *        w;
    c[6] = (1.f - u) *        v  *        w;
    c[7] =        u  *        v  *        w;

    const bool owner = (cx >= x0) && (cy >= y0);

    // Phase 2: predicated value accumulation + LDS atomic scatter.
    float vx = 0.f, vy = 0.f, vz = 0.f;
    #pragma unroll
    for (int q = 0; q < 4; ++q) {
        if (owner) {
            vx += c[q] * lo[q][0] + c[q + 4] * hi[q][0];
            vy += c[q] * lo[q][1] + c[q + 4] * hi[q][1];
            vz += c[q] * lo[q][2] + c[q + 4] * hi[q][2];
        }
        const int xi = (q & 1) ? xs1 : cx;
        const int yi = (q & 2) ? ys1 : cy;
        const int sxi = xi - x0, syi = yi - y0;
        if (sxi >= 0 && sxi < 4 && syi >= 0 && syi < 4) {
            const int col = ((sxi * 4 + syi) * 128) * 3;
            const float laml = fast_sigmoid(lrsw * c[q]);
            const int sal = col + mz * 3;
            atomicAdd(&s_acc[sal + 0], laml * (tx - lo[q][0]));
            atomicAdd(&s_acc[sal + 1], laml * (ty - lo[q][1]));
            atomicAdd(&s_acc[sal + 2], laml * (tz - lo[q][2]));
            const float lamh = fast_sigmoid(lrsw * c[q + 4]);
            const int sah = col + zs1 * 3;
            atomicAdd(&s_acc[sah + 0], lamh * (tx - hi[q][0]));
            atomicAdd(&s_acc[sah + 1], lamh * (ty - hi[q][1]));
            atomicAdd(&s_acc[sah + 2], lamh * (tz - hi[q][2]));
        }
    }
    if (owner) {
        out_value[3 * idx + 0] = vx;
        out_value[3 * idx + 1] = vy;
        out_value[3 * idx + 2] = vz;
    }
}

// cap==0: counts = binstart prefix array, payloads compact in `sorted`.
// cap>0 : counts = hist (clamped at cap), payloads at key*cap, + overflow list.
__global__ __launch_bounds__(256, 6) void brick_kernel(
    const unsigned* __restrict__ counts,
    const uint4*    __restrict__ sorted,
    const float*    __restrict__ voxel_in,
    float*          __restrict__ out_value,
    float*          __restrict__ out_voxel,
    int cap,
    const unsigned* __restrict__ ovf_key,
    const uint4*    __restrict__ ovf_pay,
    const unsigned* __restrict__ ovfcnt)
{
    __shared__ __align__(16) float s_acc[4 * 4 * 128 * 3];   // 24576 B
    __shared__ unsigned s_start[25];
    __shared__ unsigned s_pref[26];
    __shared__ unsigned s_novf;

    // XCD-slab swizzle: each XCD gets one contiguous t-slab (L2 halo reuse).
    const int vb = ((blockIdx.x & 7) << 10) | (blockIdx.x >> 3);
    const int t  = vb >> 10;
    const int bx = (vb >> 5) & 31;
    const int by = vb & 31;
    const int x0 = bx << 2, y0 = by << 2;
    const int tid = threadIdx.x;
    const size_t tbase = (size_t)t * (GRES * GRES * GRES * 3);

    float4* s_acc4 = (float4*)s_acc;
    for (int q = tid; q < 16 * 96; q += 256) s_acc4[q] = make_float4(0.f, 0.f, 0.f, 0.f);

    // wave-parallel halo-bin setup + prefix scan (wave 0)
    if (tid < 64) {
        unsigned st = 0, cnt = 0;
        if (tid < 25) {
            int dxb = tid / 5 - 1, dyb = tid % 5 - 1;
            int cx = x0 + dxb, cy = y0 + dyb;
            if (cx >= 0 && cx < GRES && cy >= 0 && cy < GRES) {
                unsigned key = ((unsigned)t << 14) | ((unsigned)cx << 7) | (unsigned)cy;
                if (cap > 0) {
                    st  = key * (unsigned)cap;
                    cnt = min(counts[key], (unsigned)cap);
                } else {
                    st  = counts[key];
                    cnt = counts[key + 1] - st;
                }
            }
            s_start[tid] = st;
        }
        unsigned x = cnt;
        #pragma unroll
        for (int off = 1; off < 32; off <<= 1) {
            unsigned y = __shfl_up(x, off);
            if (tid >= off) x += y;
        }
        if (tid < 25) s_pref[tid + 1] = x;          // inclusive scan
        if (tid == 0) s_pref[0] = 0;
    }
    if (tid == 64) s_novf = (cap > 0) ? *ovfcnt : 0u;
    __syncthreads();
    const int P = (int)s_pref[25];

    for (int j = tid; j < P; j += 256) {
        // binary search: largest b in [0,24] with s_pref[b] <= j
        int b = 0;
        #pragma unroll
        for (int s = 16; s > 0; s >>= 1) {
            int nb = b + s;
            if (nb <= 24 && s_pref[nb] <= (unsigned)j) b = nb;
        }
        const int cx = x0 + b / 5 - 1, cy = y0 + b % 5 - 1;
        const unsigned g = s_start[b] + ((unsigned)j - s_pref[b]);
        process_event(sorted[g], cx, cy, x0, y0, tbase, voxel_in, out_value, s_acc);
    }

    // overflow sweep (cap mode only; expected ~700 entries total)
    if (cap > 0) {
        const unsigned novf = min(s_novf, (unsigned)OVF_MAX);
        for (unsigned o = tid; o < novf; o += 256) {
            const unsigned key = ovf_key[o];
            if ((int)(key >> 14) != t) continue;
            const int ocx = (int)((key >> 7) & 127u), ocy = (int)(key & 127u);
            const int dxb = ocx - x0, dyb = ocy - y0;
            if (dxb < -1 || dxb > 3 || dyb < -1 || dyb > 3) continue;
            process_event(ovf_pay[o], ocx, ocy, x0, y0, tbase, voxel_in, out_value, s_acc);
        }
    }
    __syncthreads();

    // Coalesced write-out: out = voxel_in (L2/L3-hot re-read) + diff.
    for (int q = tid; q < 16 * 96; q += 256) {
        int row = q / 96, r = q - row * 96;
        int ox = row >> 2, oy = row & 3;
        const size_t coff = tbase + (size_t)(x0 + ox) * 49152 + (size_t)(y0 + oy) * 384;
        float4 a = *((const float4*)(voxel_in + coff) + r);
        float4 d = s_acc4[q];
        *((float4*)(out_voxel + coff) + r) =
            make_float4(a.x + d.x, a.y + d.y, a.z + d.z, a.w + d.w);
    }
}

extern "C" void kernel_launch(void* const* d_in, const int* in_sizes, int n_in,
                              void* d_out, int out_size, void* d_ws, size_t ws_size,
                              hipStream_t stream) {
    const int*   t      = (const int*)  d_in[0];
    const float* pos    = (const float*)d_in[1];
    const float* lr     = (const float*)d_in[2];
    const float* sigma  = (const float*)d_in[3];
    const float* target = (const float*)d_in[4];
    const float* voxel  = (const float*)d_in[5];

    const int N = in_sizes[0];              // 1048576 points

    float* out_value = (float*)d_out;
    float* out_voxel = out_value + (size_t)3 * N;

    const int block = 256;
    const int grid  = (N + block - 1) / block;

    const size_t need = (size_t)NBINS * CAP * 16 + (size_t)NBINS * 4 + 64
                      + (size_t)OVF_MAX * 4 + (size_t)OVF_MAX * 16;   // ~33.4MB

    if (ws_size >= need) {
        // ws: bins(32MB) | hist(512KB) | ovfcnt(64B) | ovf_key(64KB) | ovf_pay(256KB)
        uint4*    bins    = (uint4*)d_ws;
        unsigned* hist    = (unsigned*)(bins + (size_t)NBINS * CAP);
        unsigned* ovfcnt  = hist + NBINS;
        unsigned* ovf_key = ovfcnt + 16;
        uint4*    ovf_pay = (uint4*)(ovf_key + OVF_MAX);

        hipMemsetAsync(hist, 0, NBINS * sizeof(unsigned) + 64, stream);
        place_kernel<<<grid, block, 0, stream>>>(t, pos, lr, sigma, target,
                                                 hist, bins, ovfcnt, ovf_key,
                                                 ovf_pay, N);
        brick_kernel<<<8192, 256, 0, stream>>>(hist, bins, voxel,
                                               out_value, out_voxel,
                                               CAP, ovf_key, ovf_pay, ovfcnt);
    } else {
        // fallback: proven R5 5-kernel path (~21MB)
        uint4*    sorted   = (uint4*)d_ws;
        unsigned* keys     = (unsigned*)(sorted + (size_t)N);
        unsigned* hist     = keys + N;
        unsigned* binstart = hist + NBINS;
        unsigned* partial  = binstart + (NBINS + 1);

        hipMemsetAsync(hist, 0, NBINS * sizeof(unsigned), stream);
        key_hist_kernel<<<grid, block, 0, stream>>>(t, pos, keys, hist, N);
        scanA_kernel<<<SCAN_BLOCKS, 256, 0, stream>>>(hist, binstart, partial);
        scanC_kernel<<<SCAN_BLOCKS, 256, 0, stream>>>(binstart, partial, N);
        scatter_kernel<<<grid, block, 0, stream>>>(pos, lr, sigma, target, keys,
                                                   binstart, sorted, N);
        brick_kernel<<<8192, 256, 0, stream>>>(binstart, sorted, voxel,
                                               out_value, out_voxel,
                                               0, nullptr, nullptr, nullptr);
    }
}